// Round 2
// baseline (775.200 us; speedup 1.0000x reference)
//
#include <hip/hip_runtime.h>
#include <math.h>

#define EPS 1e-5f

static constexpr int Bc   = 32;
static constexpr int Sc   = 4096;
static constexpr int Hc   = 1024;
static constexpr int ROWS = Bc * Sc;        // 131072
static constexpr int CHUNK  = 64;           // seq rows per k3 block
static constexpr int NCHUNK = Sc / CHUNK;   // 64

// ---------- wave (64-lane) reductions ----------
__device__ __forceinline__ float waveSum(float v) {
#pragma unroll
  for (int off = 32; off > 0; off >>= 1) v += __shfl_xor(v, off, 64);
  return v;
}
__device__ __forceinline__ float waveMax(float v) {
#pragma unroll
  for (int off = 32; off > 0; off >>= 1) v = fmaxf(v, __shfl_xor(v, off, 64));
  return v;
}
__device__ __forceinline__ float blockSum(float v, float* red) {
  const int lane = threadIdx.x & 63, wid = threadIdx.x >> 6;
  const int nw = blockDim.x >> 6;
  v = waveSum(v);
  if (lane == 0) red[wid] = v;
  __syncthreads();
  if (wid == 0) {
    float t = (lane < nw) ? red[lane] : 0.0f;
    t = waveSum(t);
    if (lane == 0) red[0] = t;
  }
  __syncthreads();
  float r = red[0];
  __syncthreads();
  return r;
}
__device__ __forceinline__ float blockMax(float v, float* red) {
  const int lane = threadIdx.x & 63, wid = threadIdx.x >> 6;
  const int nw = blockDim.x >> 6;
  v = waveMax(v);
  if (lane == 0) red[wid] = v;
  __syncthreads();
  if (wid == 0) {
    float t = (lane < nw) ? red[lane] : -INFINITY;
    t = waveMax(t);
    if (lane == 0) red[0] = t;
  }
  __syncthreads();
  float r = red[0];
  __syncthreads();
  return r;
}

// ---------- pass 1: per-row {mu, rstd, dot(x, g*w)} — one wave per row ----------
// H = 1024 = 64 lanes * 4 iters * 4 floats
__global__ __launch_bounds__(256) void k1_rowstats(
    const float* __restrict__ x, const float* __restrict__ g,
    const float* __restrict__ w,
    float* __restrict__ mu_o, float* __restrict__ rstd_o,
    float* __restrict__ t_o)
{
  const int lane = threadIdx.x & 63;
  const int wv   = threadIdx.x >> 6;
  const long long row = (long long)blockIdx.x * 4 + wv;
  const float4* xr = (const float4*)(x + row * Hc);
  const float4* gr = (const float4*)g;
  const float4* wr = (const float4*)w;
  float s1 = 0.f, s2 = 0.f, t = 0.f;
#pragma unroll
  for (int k = 0; k < 4; k++) {
    const float4 xv  = xr[lane + k * 64];
    const float4 gv  = gr[lane + k * 64];
    const float4 wv4 = wr[lane + k * 64];
    s1 += xv.x + xv.y + xv.z + xv.w;
    s2 += xv.x*xv.x + xv.y*xv.y + xv.z*xv.z + xv.w*xv.w;
    t  += xv.x*gv.x*wv4.x + xv.y*gv.y*wv4.y + xv.z*gv.z*wv4.z + xv.w*gv.w*wv4.w;
  }
  s1 = waveSum(s1);
  s2 = waveSum(s2);
  t  = waveSum(t);
  if (lane == 0) {
    float mu   = s1 * (1.0f / Hc);
    float var  = s2 * (1.0f / Hc) - mu * mu;
    float rstd = rsqrtf(var + EPS);
    mu_o[row]   = mu;
    rstd_o[row] = rstd;
    t_o[row]    = t;
  }
}

// ---------- pass 2: per-batch softmax; emit c[s] = w_s*rstd_s and d_b ----------
__global__ __launch_bounds__(1024) void k2_softmax(
    const float* __restrict__ g, const float* __restrict__ w,
    const float* __restrict__ beta,
    const float* __restrict__ mu, const float* __restrict__ rstd,
    const float* __restrict__ tdot,
    float* __restrict__ c, float* __restrict__ dvec)
{
  __shared__ float red[16];
  const int b   = blockIdx.x;
  const int tid = threadIdx.x;

  // sgw = sum(g*w), bw = dot(beta, w); H == blockDim.x == 1024
  const float gv = g[tid], wv = w[tid], bv = beta[tid];
  const float sgw = blockSum(gv * wv, red);
  const float bw  = blockSum(bv * wv, red);

  float sc[4], mus[4], rst[4];
  float localmax = -INFINITY;
#pragma unroll
  for (int k = 0; k < 4; k++) {
    const int row = b * Sc + tid + k * 1024;
    const float m = mu[row], r = rstd[row], t = tdot[row];
    const float s = r * (t - m * sgw) + bw;
    sc[k] = s; mus[k] = m; rst[k] = r;
    localmax = fmaxf(localmax, s);
  }
  const float smax = blockMax(localmax, red);

  float e[4], zp = 0.0f;
#pragma unroll
  for (int k = 0; k < 4; k++) {
    const float v = fminf(fmaxf(sc[k] - smax, -10.0f), 10.0f);
    e[k] = expf(v);
    zp += e[k];
  }
  const float Z = blockSum(zp, red);
  const float invZ = 1.0f / Z;

  float dp = 0.0f;
#pragma unroll
  for (int k = 0; k < 4; k++) {
    const float cv = e[k] * invZ * rst[k];
    c[b * Sc + tid + k * 1024] = cv;
    dp += cv * mus[k];
  }
  const float d = blockSum(dp, red);
  if (tid == 0) dvec[b] = d;
}

// ---------- pass 3: out[b,h] = g[h]*(sum_s c_s*x[b,s,h] - d_b) + beta[h] ----------
__global__ __launch_bounds__(256) void k3_wsum(
    const float* __restrict__ x, const float* __restrict__ c,
    const float* __restrict__ dvec, const float* __restrict__ g,
    const float* __restrict__ beta, float* __restrict__ out)
{
  __shared__ float cs[CHUNK];
  const int chunk = blockIdx.x;
  const int b     = blockIdx.y;
  const int t     = threadIdx.x;
  const int s0    = chunk * CHUNK;
  if (t < CHUNK) cs[t] = c[b * Sc + s0 + t];
  __syncthreads();

  const float4* xp = (const float4*)(x + (long long)(b * Sc + s0) * Hc) + t;
  float4 acc = make_float4(0.f, 0.f, 0.f, 0.f);
#pragma unroll 4
  for (int i = 0; i < CHUNK; i++) {
    const float cv = cs[i];
    const float4 xv = xp[i * (Hc / 4)];
    acc.x = fmaf(cv, xv.x, acc.x);
    acc.y = fmaf(cv, xv.y, acc.y);
    acc.z = fmaf(cv, xv.z, acc.z);
    acc.w = fmaf(cv, xv.w, acc.w);
  }
  const float4 gv = ((const float4*)g)[t];
  const float4 bv = ((const float4*)beta)[t];
  float4 res;
  res.x = gv.x * acc.x;
  res.y = gv.y * acc.y;
  res.z = gv.z * acc.z;
  res.w = gv.w * acc.w;
  if (chunk == 0) {  // fold the "+ beta - g*d" epilogue into exactly one chunk
    const float d = dvec[b];
    res.x += bv.x - gv.x * d;
    res.y += bv.y - gv.y * d;
    res.z += bv.z - gv.z * d;
    res.w += bv.w - gv.w * d;
  }
  float* o = out + b * Hc + t * 4;
  atomicAdd(o + 0, res.x);
  atomicAdd(o + 1, res.y);
  atomicAdd(o + 2, res.z);
  atomicAdd(o + 3, res.w);
}

extern "C" void kernel_launch(void* const* d_in, const int* in_sizes, int n_in,
                              void* d_out, int out_size, void* d_ws, size_t ws_size,
                              hipStream_t stream) {
  const float* x    = (const float*)d_in[0];  // [B,S,H]
  const float* g    = (const float*)d_in[1];  // [H]
  const float* beta = (const float*)d_in[2];  // [H]
  const float* w    = (const float*)d_in[3];  // [H]
  float* out = (float*)d_out;                 // [B,H]

  float* mu   = (float*)d_ws;        // ROWS
  float* rstd = mu   + ROWS;         // ROWS
  float* tdot = rstd + ROWS;         // ROWS
  float* c    = tdot + ROWS;         // ROWS
  float* dvec = c    + ROWS;         // Bc
  // total ws use: (4*131072 + 32) * 4B ~= 2.0 MB

  hipMemsetAsync(d_out, 0, (size_t)Bc * Hc * sizeof(float), stream);
  k1_rowstats<<<ROWS / 4, 256, 0, stream>>>(x, g, w, mu, rstd, tdot);
  k2_softmax<<<Bc, 1024, 0, stream>>>(g, w, beta, mu, rstd, tdot, c, dvec);
  dim3 grid3(NCHUNK, Bc);
  k3_wsum<<<grid3, 256, 0, stream>>>(x, c, dvec, g, beta, out);
}

// Round 3
// 769.337 us; speedup vs baseline: 1.0076x; 1.0076x over previous
//
#include <hip/hip_runtime.h>
#include <math.h>

#define EPS 1e-5f

static constexpr int Bc   = 32;
static constexpr int Sc   = 4096;
static constexpr int Hc   = 1024;
static constexpr int ROWS = Bc * Sc;      // 131072
static constexpr int SSPLIT = 32;         // s-chunks for pass 3 stage 1
static constexpr int RPC    = Sc / SSPLIT; // 128 rows per chunk

// ---------- wave (64-lane) reductions ----------
__device__ __forceinline__ float waveSum(float v) {
#pragma unroll
  for (int off = 32; off > 0; off >>= 1) v += __shfl_xor(v, off, 64);
  return v;
}
__device__ __forceinline__ void waveSum3(float& a, float& b, float& c) {
#pragma unroll
  for (int off = 32; off > 0; off >>= 1) {
    a += __shfl_xor(a, off, 64);
    b += __shfl_xor(b, off, 64);
    c += __shfl_xor(c, off, 64);
  }
}
__device__ __forceinline__ float waveMax(float v) {
#pragma unroll
  for (int off = 32; off > 0; off >>= 1) v = fmaxf(v, __shfl_xor(v, off, 64));
  return v;
}
__device__ __forceinline__ float blockSum(float v, float* red) {
  const int lane = threadIdx.x & 63, wid = threadIdx.x >> 6;
  const int nw = blockDim.x >> 6;
  v = waveSum(v);
  if (lane == 0) red[wid] = v;
  __syncthreads();
  if (wid == 0) {
    float t = (lane < nw) ? red[lane] : 0.0f;
    t = waveSum(t);
    if (lane == 0) red[0] = t;
  }
  __syncthreads();
  float r = red[0];
  __syncthreads();
  return r;
}
__device__ __forceinline__ float blockMax(float v, float* red) {
  const int lane = threadIdx.x & 63, wid = threadIdx.x >> 6;
  const int nw = blockDim.x >> 6;
  v = waveMax(v);
  if (lane == 0) red[wid] = v;
  __syncthreads();
  if (wid == 0) {
    float t = (lane < nw) ? red[lane] : -INFINITY;
    t = waveMax(t);
    if (lane == 0) red[0] = t;
  }
  __syncthreads();
  float r = red[0];
  __syncthreads();
  return r;
}

// ---------- pass 0: gw = g*w ; scalars {sgw, bw} ----------
__global__ __launch_bounds__(1024) void k0_prep(
    const float* __restrict__ g, const float* __restrict__ w,
    const float* __restrict__ beta,
    float* __restrict__ gw, float* __restrict__ scal)
{
  __shared__ float red[16];
  const int tid = threadIdx.x;
  const float gv = g[tid], wv = w[tid], bv = beta[tid];
  gw[tid] = gv * wv;
  const float sgw = blockSum(gv * wv, red);
  const float bw  = blockSum(bv * wv, red);
  if (tid == 0) { scal[0] = sgw; scal[1] = bw; }
}

// ---------- pass 1: per-row {mu, rstd, dot(x,gw)} — one wave per row ----------
// H = 1024 = 64 lanes * 4 iters * 4 floats
__global__ __launch_bounds__(256) void k1_rowstats(
    const float* __restrict__ x, const float* __restrict__ gw,
    float* __restrict__ mu_o, float* __restrict__ rstd_o,
    float* __restrict__ t_o)
{
  const int lane = threadIdx.x & 63;
  const int wv   = threadIdx.x >> 6;
  const long long row = (long long)blockIdx.x * 4 + wv;
  const float4* xr = (const float4*)(x + row * Hc);
  const float4* gr = (const float4*)gw;
  float s1 = 0.f, s2 = 0.f, t = 0.f;
#pragma unroll
  for (int k = 0; k < 4; k++) {
    const float4 xv = xr[lane + k * 64];
    const float4 gv = gr[lane + k * 64];
    s1 += xv.x + xv.y + xv.z + xv.w;
    s2 += xv.x*xv.x + xv.y*xv.y + xv.z*xv.z + xv.w*xv.w;
    t  += xv.x*gv.x + xv.y*gv.y + xv.z*gv.z + xv.w*gv.w;
  }
  waveSum3(s1, s2, t);
  if (lane == 0) {
    float mu   = s1 * (1.0f / Hc);
    float var  = s2 * (1.0f / Hc) - mu * mu;
    float rstd = rsqrtf(var + EPS);
    mu_o[row]   = mu;
    rstd_o[row] = rstd;
    t_o[row]    = t;
  }
}

// ---------- pass 2: per-batch softmax; emit c[s] = w_s*rstd_s and d_b ----------
__global__ __launch_bounds__(1024) void k2_softmax(
    const float* __restrict__ scal,
    const float* __restrict__ mu, const float* __restrict__ rstd,
    const float* __restrict__ tdot,
    float* __restrict__ c, float* __restrict__ dvec)
{
  __shared__ float red[16];
  const int b   = blockIdx.x;
  const int tid = threadIdx.x;
  const float sgw = scal[0];
  const float bw  = scal[1];

  float sc[4], mus[4], rst[4];
  float localmax = -INFINITY;
#pragma unroll
  for (int k = 0; k < 4; k++) {
    const int row = b * Sc + tid + k * 1024;
    const float m = mu[row], r = rstd[row], t = tdot[row];
    const float s = r * (t - m * sgw) + bw;
    sc[k] = s; mus[k] = m; rst[k] = r;
    localmax = fmaxf(localmax, s);
  }
  const float smax = blockMax(localmax, red);

  float e[4], zp = 0.0f;
#pragma unroll
  for (int k = 0; k < 4; k++) {
    const float v = fminf(fmaxf(sc[k] - smax, -10.0f), 10.0f);
    e[k] = expf(v);
    zp += e[k];
  }
  const float Z = blockSum(zp, red);
  const float invZ = 1.0f / Z;

  float dp = 0.0f;
#pragma unroll
  for (int k = 0; k < 4; k++) {
    const float cv = e[k] * invZ * rst[k];
    c[b * Sc + tid + k * 1024] = cv;
    dp += cv * mus[k];
  }
  const float d = blockSum(dp, red);
  if (tid == 0) dvec[b] = d;
}

// ---------- pass 3 stage 1: partial[b,chunk,h] = sum_{s in chunk} c_s * x[b,s,h] ----------
__global__ __launch_bounds__(256) void k3_partial(
    const float* __restrict__ x, const float* __restrict__ c,
    float* __restrict__ part)
{
  __shared__ float cs[RPC];
  const int chunk = blockIdx.x;   // 0..SSPLIT-1
  const int b     = blockIdx.y;   // 0..Bc-1
  const int t     = threadIdx.x;  // 0..255, float4 column
  const int s0    = chunk * RPC;
  // load chunk's c values (128 floats) into LDS
  if (t < RPC) cs[t] = c[b * Sc + s0 + t];
  __syncthreads();

  const float4* xp = (const float4*)(x + (long long)(b * Sc + s0) * Hc) + t;
  float4 acc = make_float4(0.f, 0.f, 0.f, 0.f);
#pragma unroll 4
  for (int i = 0; i < RPC; i++) {
    const float cv = cs[i];
    const float4 xv = xp[i * (Hc / 4)];
    acc.x = fmaf(cv, xv.x, acc.x);
    acc.y = fmaf(cv, xv.y, acc.y);
    acc.z = fmaf(cv, xv.z, acc.z);
    acc.w = fmaf(cv, xv.w, acc.w);
  }
  float4* pp = (float4*)(part + ((long long)(b * SSPLIT + chunk)) * Hc) + t;
  *pp = acc;
}

// ---------- pass 3 stage 2: out[b,h] = g*(sum_chunks - d_b) + beta ----------
__global__ __launch_bounds__(256) void k4_final(
    const float* __restrict__ part, const float* __restrict__ dvec,
    const float* __restrict__ g, const float* __restrict__ beta,
    float* __restrict__ out)
{
  const int b = blockIdx.x;
  const int t = threadIdx.x;
  const float4* pp = (const float4*)(part + (long long)b * SSPLIT * Hc) + t;
  float4 acc = make_float4(0.f, 0.f, 0.f, 0.f);
#pragma unroll
  for (int j = 0; j < SSPLIT; j++) {
    const float4 pv = pp[j * (Hc / 4)];
    acc.x += pv.x; acc.y += pv.y; acc.z += pv.z; acc.w += pv.w;
  }
  const float d = dvec[b];
  const float4 gv = ((const float4*)g)[t];
  const float4 bv = ((const float4*)beta)[t];
  float4 res;
  res.x = gv.x * (acc.x - d) + bv.x;
  res.y = gv.y * (acc.y - d) + bv.y;
  res.z = gv.z * (acc.z - d) + bv.z;
  res.w = gv.w * (acc.w - d) + bv.w;
  ((float4*)(out + b * Hc))[t] = res;
}

extern "C" void kernel_launch(void* const* d_in, const int* in_sizes, int n_in,
                              void* d_out, int out_size, void* d_ws, size_t ws_size,
                              hipStream_t stream) {
  const float* x    = (const float*)d_in[0];  // [B,S,H]
  const float* g    = (const float*)d_in[1];  // [H]
  const float* beta = (const float*)d_in[2];  // [H]
  const float* w    = (const float*)d_in[3];  // [H]
  float* out = (float*)d_out;                 // [B,H]

  float* gw   = (float*)d_ws;            // Hc
  float* scal = gw + Hc;                 // 2
  float* mu   = scal + 2;                // ROWS
  float* rstd = mu + ROWS;               // ROWS
  float* tdot = rstd + ROWS;             // ROWS
  float* c    = tdot + ROWS;             // ROWS
  float* dvec = c + ROWS;                // Bc
  float* part = dvec + Bc;               // Bc*SSPLIT*Hc = 1M floats
  // total ws use ~ 6.3 MB

  k0_prep<<<1, 1024, 0, stream>>>(g, w, beta, gw, scal);
  k1_rowstats<<<ROWS / 4, 256, 0, stream>>>(x, gw, mu, rstd, tdot);
  k2_softmax<<<Bc, 1024, 0, stream>>>(scal, mu, rstd, tdot, c, dvec);
  dim3 grid3(SSPLIT, Bc);
  k3_partial<<<grid3, 256, 0, stream>>>(x, c, part);
  k4_final<<<Bc, 256, 0, stream>>>(part, dvec, g, beta, out);
}

// Round 4
// 697.170 us; speedup vs baseline: 1.1119x; 1.1035x over previous
//
#include <hip/hip_runtime.h>
#include <math.h>

#define EPS 1e-5f

static constexpr int Bc   = 32;
static constexpr int Sc   = 4096;
static constexpr int Hc   = 1024;
static constexpr int RPW    = 32;                  // rows per wave-chunk
static constexpr int CPB    = Sc / RPW;            // 128 chunks per batch
static constexpr int NCHUNK = Bc * CPB;            // 4096 wave-chunks total

// ---------- wave (64-lane) reductions ----------
__device__ __forceinline__ float waveSum(float v) {
#pragma unroll
  for (int off = 32; off > 0; off >>= 1) v += __shfl_xor(v, off, 64);
  return v;
}
__device__ __forceinline__ void waveSum3(float& a, float& b, float& c) {
#pragma unroll
  for (int off = 32; off > 0; off >>= 1) {
    a += __shfl_xor(a, off, 64);
    b += __shfl_xor(b, off, 64);
    c += __shfl_xor(c, off, 64);
  }
}
__device__ __forceinline__ float waveMax(float v) {
#pragma unroll
  for (int off = 32; off > 0; off >>= 1) v = fmaxf(v, __shfl_xor(v, off, 64));
  return v;
}
__device__ __forceinline__ float blockSum(float v, float* red) {
  const int lane = threadIdx.x & 63, wid = threadIdx.x >> 6;
  const int nw = blockDim.x >> 6;
  v = waveSum(v);
  if (lane == 0) red[wid] = v;
  __syncthreads();
  if (wid == 0) {
    float t = (lane < nw) ? red[lane] : 0.0f;
    t = waveSum(t);
    if (lane == 0) red[0] = t;
  }
  __syncthreads();
  float r = red[0];
  __syncthreads();
  return r;
}
__device__ __forceinline__ float blockMax(float v, float* red) {
  const int lane = threadIdx.x & 63, wid = threadIdx.x >> 6;
  const int nw = blockDim.x >> 6;
  v = waveMax(v);
  if (lane == 0) red[wid] = v;
  __syncthreads();
  if (wid == 0) {
    float t = (lane < nw) ? red[lane] : -INFINITY;
    t = waveMax(t);
    if (lane == 0) red[0] = t;
  }
  __syncthreads();
  float r = red[0];
  __syncthreads();
  return r;
}

// ---------- pass 0: gw = g*w ; scalars {sgw, bw} ----------
__global__ __launch_bounds__(1024) void k0_prep(
    const float* __restrict__ g, const float* __restrict__ w,
    const float* __restrict__ beta,
    float* __restrict__ gw, float* __restrict__ scal)
{
  __shared__ float red[16];
  const int tid = threadIdx.x;
  const float gv = g[tid], wv = w[tid], bv = beta[tid];
  gw[tid] = gv * wv;
  const float sgw = blockSum(gv * wv, red);
  const float bw  = blockSum(bv * wv, red);
  if (tid == 0) { scal[0] = sgw; scal[1] = bw; }
}

// ---------- pass 1: single read of x — online softmax per 32-row wave-chunk ----
// One wave per chunk. Lane holds 16 row elements (4 x float4). Per row:
// wave-reduce {sum, sumsq, dot(x,gw)} -> mu, rstd, score; online update of
// (m, Z, D, O[h]) where O += e*rstd*x, D += e*rstd*mu, Z += e.
__global__ __launch_bounds__(256) void k1_online(
    const float* __restrict__ x, const float* __restrict__ gw,
    const float* __restrict__ scal,
    float* __restrict__ part,    // [NCHUNK][1024] unscaled O_c
    float* __restrict__ mzd)     // [NCHUNK] float4 {m, Z, D, -}
{
  const int lane  = threadIdx.x & 63;
  const int wid   = threadIdx.x >> 6;
  const int chunk = blockIdx.x * 4 + wid;          // 0..NCHUNK-1

  const float sgw = scal[0];
  const float bw  = scal[1];

  const float4* gr = (const float4*)gw;
  float4 gwf[4];
#pragma unroll
  for (int k = 0; k < 4; k++) gwf[k] = gr[lane + k * 64];

  // rows of this chunk are globally contiguous: row = chunk*RPW + r
  const float4* xr = (const float4*)x + (size_t)chunk * RPW * (Hc / 4);

  float m = -INFINITY, Z = 0.f, D = 0.f;
  float4 O[4];
#pragma unroll
  for (int k = 0; k < 4; k++) O[k] = make_float4(0.f, 0.f, 0.f, 0.f);

  float4 cur[4], nxt[4];
#pragma unroll
  for (int k = 0; k < 4; k++) cur[k] = xr[lane + k * 64];

#pragma unroll 2
  for (int r = 0; r < RPW; r++) {
    const int rn = (r < RPW - 1) ? r + 1 : r;      // clamp: avoid OOB prefetch
    const float4* nx = xr + rn * (Hc / 4);
#pragma unroll
    for (int k = 0; k < 4; k++) nxt[k] = nx[lane + k * 64];

    float s1 = 0.f, s2 = 0.f, t = 0.f;
#pragma unroll
    for (int k = 0; k < 4; k++) {
      const float4 v = cur[k];
      s1 += v.x + v.y + v.z + v.w;
      s2 = fmaf(v.x, v.x, fmaf(v.y, v.y, fmaf(v.z, v.z, fmaf(v.w, v.w, s2))));
      const float4 gv = gwf[k];
      t = fmaf(v.x, gv.x, fmaf(v.y, gv.y, fmaf(v.z, gv.z, fmaf(v.w, gv.w, t))));
    }
    waveSum3(s1, s2, t);
    const float mu   = s1 * (1.0f / Hc);
    const float var  = fmaf(-mu, mu, s2 * (1.0f / Hc));
    const float rstd = rsqrtf(var + EPS);
    const float sc   = fmaf(rstd, fmaf(-mu, sgw, t), bw);

    if (sc > m) {                      // wave-uniform branch
      const float a = expf(m - sc);    // first row: expf(-inf)=0 zeroes state
      Z = fmaf(Z, a, 1.0f);
      D = fmaf(D, a, rstd * mu);
#pragma unroll
      for (int k = 0; k < 4; k++) {
        O[k].x = fmaf(O[k].x, a, rstd * cur[k].x);
        O[k].y = fmaf(O[k].y, a, rstd * cur[k].y);
        O[k].z = fmaf(O[k].z, a, rstd * cur[k].z);
        O[k].w = fmaf(O[k].w, a, rstd * cur[k].w);
      }
      m = sc;
    } else {
      const float e  = expf(sc - m);
      const float er = e * rstd;
      Z += e;
      D = fmaf(er, mu, D);
#pragma unroll
      for (int k = 0; k < 4; k++) {
        O[k].x = fmaf(er, cur[k].x, O[k].x);
        O[k].y = fmaf(er, cur[k].y, O[k].y);
        O[k].z = fmaf(er, cur[k].z, O[k].z);
        O[k].w = fmaf(er, cur[k].w, O[k].w);
      }
    }
#pragma unroll
    for (int k = 0; k < 4; k++) cur[k] = nxt[k];
  }

  float4* pp = (float4*)part + (size_t)chunk * (Hc / 4);
#pragma unroll
  for (int k = 0; k < 4; k++) pp[lane + k * 64] = O[k];
  if (lane == 0) ((float4*)mzd)[chunk] = make_float4(m, Z, D, 0.f);
}

// ---------- pass 2: combine 128 chunk-partials per batch, apply epilogue ----
__global__ __launch_bounds__(256) void k2_combine(
    const float* __restrict__ part, const float* __restrict__ mzd,
    const float* __restrict__ g, const float* __restrict__ beta,
    float* __restrict__ out)
{
  __shared__ float sf[CPB];
  __shared__ float red[16];
  const int b = blockIdx.x;
  const int t = threadIdx.x;

  float4 v = make_float4(-INFINITY, 0.f, 0.f, 0.f);
  if (t < CPB) v = ((const float4*)mzd)[b * CPB + t];
  const float M = blockMax(v.x, red);
  float fj = 0.f, Zj = 0.f, Dj = 0.f;
  if (t < CPB) {
    fj = expf(v.x - M);
    Zj = v.y * fj;
    Dj = v.z * fj;
    sf[t] = fj;
  }
  const float Z = blockSum(Zj, red);   // barriers inside make sf[] visible
  const float D = blockSum(Dj, red);

  const float4* pp = (const float4*)part + (size_t)b * CPB * (Hc / 4) + t;
  float4 acc = make_float4(0.f, 0.f, 0.f, 0.f);
#pragma unroll 8
  for (int j = 0; j < CPB; j++) {
    const float f = sf[j];
    const float4 pv = pp[(size_t)j * (Hc / 4)];
    acc.x = fmaf(f, pv.x, acc.x);
    acc.y = fmaf(f, pv.y, acc.y);
    acc.z = fmaf(f, pv.z, acc.z);
    acc.w = fmaf(f, pv.w, acc.w);
  }
  const float invZ = 1.0f / Z;
  const float4 gv = ((const float4*)g)[t];
  const float4 bv = ((const float4*)beta)[t];
  float4 res;
  res.x = fmaf(gv.x * invZ, acc.x - D, bv.x);
  res.y = fmaf(gv.y * invZ, acc.y - D, bv.y);
  res.z = fmaf(gv.z * invZ, acc.z - D, bv.z);
  res.w = fmaf(gv.w * invZ, acc.w - D, bv.w);
  ((float4*)out)[b * (Hc / 4) + t] = res;
}

extern "C" void kernel_launch(void* const* d_in, const int* in_sizes, int n_in,
                              void* d_out, int out_size, void* d_ws, size_t ws_size,
                              hipStream_t stream) {
  const float* x    = (const float*)d_in[0];  // [B,S,H]
  const float* g    = (const float*)d_in[1];  // [H]
  const float* beta = (const float*)d_in[2];  // [H]
  const float* w    = (const float*)d_in[3];  // [H]
  float* out = (float*)d_out;                 // [B,H]

  float* part = (float*)d_ws;                       // NCHUNK*Hc = 4M floats (16 MB)
  float* mzd  = part + (size_t)NCHUNK * Hc;         // NCHUNK float4 (64 KB)
  float* gw   = mzd + (size_t)NCHUNK * 4;           // Hc
  float* scal = gw + Hc;                            // 2

  k0_prep<<<1, 1024, 0, stream>>>(g, w, beta, gw, scal);
  k1_online<<<NCHUNK / 4, 256, 0, stream>>>(x, gw, scal, part, mzd);
  k2_combine<<<Bc, 256, 0, stream>>>(part, mzd, g, beta, out);
}